// Round 4
// baseline (459.966 us; speedup 1.0000x reference)
//
#include <hip/hip_runtime.h>
#include <hip/hip_bf16.h>
#include <stdint.h>

#define NB 4
#define NK 64
#define NL 128
#define ND 768
#define NBK (NB*NK)        // 256
#define NROW (NBK*NL)      // 32768
#define LD2 (NL*ND)        // 98304
#define EPSF 1e-8f
#define THETA 2e-3f        // candidate window on dot*einv scale (~75 sigma of split-bf16 error)
#define CAP 16384          // candidate list capacity (expect ~300)
#define TSTR 40            // k2a LDS row stride (80B = 5 slots, odd mod 8)

typedef __bf16 bf16x8 __attribute__((ext_vector_type(8)));
typedef float  f32x4  __attribute__((ext_vector_type(4)));

// Row space r in [0, 2*NROW): [0,NROW) = ctx rows (bk=r>>7, l=r&127),
// [NROW,2*NROW) = ent rows. Returns float offset into context tensor.
__device__ __forceinline__ int row_off(int r) {
  if (r < NROW) return r*ND + (r >> 7)*LD2;
  int r2 = r - NROW;
  return r2*ND + (r2 >> 7)*LD2 + LD2;
}

// ---------------- K0: w1 -> w1t transpose + zero-init of fixup state -------
__global__ __launch_bounds__(256) void k0_w1t(const float* __restrict__ w1,
                                              __bf16* __restrict__ w1t,
                                              unsigned long long* __restrict__ amax2,
                                              unsigned* __restrict__ cntg) {
  __shared__ float tile[64][68];               // [k][e], +4 pad
  int idx = blockIdx.x*256 + threadIdx.x;
  if (idx < NROW) amax2[idx] = 0ull;           // fixup keys zeroed every launch
  if (idx == 0) *cntg = 0u;
  int kb = (blockIdx.x / 12) * 64, eb = (blockIdx.x % 12) * 64;
  int t = threadIdx.x;
  int r = t >> 2, c0 = (t & 3) * 16;
  #pragma unroll
  for (int j = 0; j < 4; j++) {
    f32x4 v = *(const f32x4*)(w1 + (kb + r)*ND + eb + c0 + j*4);
    *(f32x4*)&tile[r][c0 + j*4] = v;
  }
  __syncthreads();
  int e = t & 63, gi = t >> 6;
  int eg = eb + e;
  #pragma unroll
  for (int g2 = 0; g2 < 2; g2++) {
    int g = gi*2 + g2;
    bf16x8 o;
    #pragma unroll
    for (int j = 0; j < 8; j++) o[j] = (__bf16)tile[g*8 + j][e];
    int G = (kb >> 3) + (g ^ (eg & 7));        // XOR layout, undone at read time
    *(bf16x8*)(w1t + eg*ND + G*8) = o;
  }
}

// split f32x4 into truncated-bf16 hi (packed pair uints) and exact-remainder
// lo (truncated to bf16); accumulate sum of squares of the f32 values.
__device__ __forceinline__ void cvt4(f32x4 v, unsigned& hp0, unsigned& hp1,
                                     unsigned& lp0, unsigned& lp1, float& sq) {
  unsigned u0 = __float_as_uint(v[0]), u1 = __float_as_uint(v[1]);
  unsigned u2 = __float_as_uint(v[2]), u3 = __float_as_uint(v[3]);
  hp0 = (u1 & 0xffff0000u) | (u0 >> 16);
  hp1 = (u3 & 0xffff0000u) | (u2 >> 16);
  float l0 = v[0] - __uint_as_float(u0 & 0xffff0000u);   // exact (Sterbenz)
  float l1 = v[1] - __uint_as_float(u1 & 0xffff0000u);
  float l2 = v[2] - __uint_as_float(u2 & 0xffff0000u);
  float l3 = v[3] - __uint_as_float(u3 & 0xffff0000u);
  lp0 = (__float_as_uint(l1) & 0xffff0000u) | (__float_as_uint(l0) >> 16);
  lp1 = (__float_as_uint(l3) & 0xffff0000u) | (__float_as_uint(l2) >> 16);
  sq += v[0]*v[0] + v[1]*v[1] + v[2]*v[2] + v[3]*v[3];
}

// RNE-rounded bf16x8 from two f32x4 (for the k3 A-mirror).
__device__ __forceinline__ bf16x8 rnd8(f32x4 a, f32x4 b) {
  bf16x8 o;
  o[0] = (__bf16)a[0]; o[1] = (__bf16)a[1]; o[2] = (__bf16)a[2]; o[3] = (__bf16)a[3];
  o[4] = (__bf16)b[0]; o[5] = (__bf16)b[1]; o[6] = (__bf16)b[2]; o[7] = (__bf16)b[3];
  return o;
}

// ---------------- K2a: MFMA cosine screen + argmax + norms + candidates ----
// One block per bk: 128 ctx x 128 ent x K=768. 512 thr = 8 waves, wave w owns
// rows w*16..+15, all 128 cols (8 col-tiles), acc = 3-product split-bf16 sum.
// Also writes a rounded-bf16 mirror of each row for k3.
__global__ __launch_bounds__(512) void k2a_screen(
    const float* __restrict__ ctxall, float* __restrict__ norm,
    int* __restrict__ amax, unsigned* __restrict__ cntg,
    unsigned* __restrict__ list, __bf16* __restrict__ abf16) {
  __shared__ alignas(16) __bf16 tiles[2][4][128*TSTR];  // [buf][ahi,alo,bhi,blo]
  __shared__ float einv_s[128];
  int bk = blockIdx.x;
  int t = threadIdx.x;
  int mat = t >> 8, row = (t >> 1) & 127, kh = (t & 1) * 16;
  const float* src = ctxall + bk*2*LD2 + mat*LD2 + row*ND + kh;
  int w = t >> 6, lane = t & 63, quad = lane >> 4, eloc = lane & 15;
  __bf16* arow = abf16 ? (abf16 + (size_t)((mat ? NROW : 0) + bk*NL + row)*ND + kh)
                       : (__bf16*)0;

  f32x4 pv[4];
  #pragma unroll
  for (int i = 0; i < 4; i++) pv[i] = *(const f32x4*)(src + i*4);
  float sq = 0.f;
  f32x4 acc[8];
  #pragma unroll
  for (int ct = 0; ct < 8; ct++) acc[ct] = (f32x4){0,0,0,0};

  int p = 0;
  for (int kt = 0; kt < 24; kt++) {
    // convert current prefetch regs -> LDS[p]
    unsigned h0,h1,h2,h3, l0,l1,l2,l3;
    cvt4(pv[0], h0, h1, l0, l1, sq);
    cvt4(pv[1], h2, h3, l2, l3, sq);
    __bf16* hdst = &tiles[p][2*mat  ][row*TSTR + kh];
    __bf16* ldst = &tiles[p][2*mat+1][row*TSTR + kh];
    *(uint4*)hdst = make_uint4(h0,h1,h2,h3);
    *(uint4*)ldst = make_uint4(l0,l1,l2,l3);
    bf16x8 rb0, rb1;
    if (arow) rb0 = rnd8(pv[0], pv[1]);
    cvt4(pv[2], h0, h1, l0, l1, sq);
    cvt4(pv[3], h2, h3, l2, l3, sq);
    *((uint4*)hdst + 1) = make_uint4(h0,h1,h2,h3);
    *((uint4*)ldst + 1) = make_uint4(l0,l1,l2,l3);
    if (arow) rb1 = rnd8(pv[2], pv[3]);
    __syncthreads();
    if (arow) {                                // A-mirror store (fire & forget)
      *(bf16x8*)(arow + kt*32) = rb0;
      *(bf16x8*)(arow + kt*32 + 8) = rb1;
    }
    if (kt < 23) {                             // prefetch next Kt (flies over compute)
      const float* s2 = src + (kt+1)*32;
      #pragma unroll
      for (int i = 0; i < 4; i++) pv[i] = *(const f32x4*)(s2 + i*4);
    }
    // compute: A-frag rows w*16+eloc, k=quad*8+j
    bf16x8 ah = *(const bf16x8*)&tiles[p][0][(w*16+eloc)*TSTR + quad*8];
    bf16x8 al = *(const bf16x8*)&tiles[p][1][(w*16+eloc)*TSTR + quad*8];
    #pragma unroll
    for (int ct = 0; ct < 8; ct++) {
      bf16x8 bh = *(const bf16x8*)&tiles[p][2][(ct*16+eloc)*TSTR + quad*8];
      bf16x8 bl = *(const bf16x8*)&tiles[p][3][(ct*16+eloc)*TSTR + quad*8];
      acc[ct] = __builtin_amdgcn_mfma_f32_16x16x32_bf16(al, bh, acc[ct], 0, 0, 0);
      acc[ct] = __builtin_amdgcn_mfma_f32_16x16x32_bf16(ah, bl, acc[ct], 0, 0, 0);
      acc[ct] = __builtin_amdgcn_mfma_f32_16x16x32_bf16(ah, bh, acc[ct], 0, 0, 0);
    }
    p ^= 1;
  }

  // norms: thread pair (t, t^1) holds the two k-halves of one row
  float stot = sq + __shfl_xor(sq, 1);
  if ((t & 1) == 0) {
    float n = sqrtf(stot);
    if (mat == 0) norm[bk*NL + row] = n;
    else { norm[NROW + bk*NL + row] = n; einv_s[row] = 1.0f / n; }
  }
  __syncthreads();

  // epilogue: per-row argmax of acc*einv + theta-window candidate push
  #pragma unroll
  for (int rr = 0; rr < 4; rr++) {
    float sc[8];
    float best = -3.0e38f; int bcol = 0;
    #pragma unroll
    for (int ct = 0; ct < 8; ct++) {
      sc[ct] = acc[ct][rr] * einv_s[ct*16 + eloc];
      int col = ct*16 + eloc;
      if (sc[ct] > best) { best = sc[ct]; bcol = col; }
    }
    #pragma unroll
    for (int m = 1; m < 16; m <<= 1) {
      float ov = __shfl_xor(best, m);
      int   oc = __shfl_xor(bcol, m);
      if (ov > best || (ov == best && oc < bcol)) { best = ov; bcol = oc; }
    }
    int grow = bk*NL + w*16 + quad*4 + rr;
    if (eloc == 0) amax[grow] = bcol;
    int cnt = 0;
    #pragma unroll
    for (int ct = 0; ct < 8; ct++) cnt += (sc[ct] >= best - THETA) ? 1 : 0;
    #pragma unroll
    for (int m = 1; m < 16; m <<= 1) cnt += __shfl_xor(cnt, m);
    if (cnt >= 2) {                            // near-tie: exact rescore needed
      #pragma unroll
      for (int ct = 0; ct < 8; ct++) {
        if (sc[ct] >= best - THETA) {
          unsigned idx = atomicAdd(cntg, 1u);
          if (idx < CAP) list[idx] = ((unsigned)grow << 7) | (unsigned)(ct*16 + eloc);
        }
      }
    }
  }
}

// ---------------- K2b: exact f32 rescore of near-tie candidates ------------
__global__ __launch_bounds__(256) void k2b_rescore(
    const float* __restrict__ ctxall, const float* __restrict__ norm,
    const unsigned* __restrict__ cntg, const unsigned* __restrict__ list,
    unsigned long long* __restrict__ amax2) {
  unsigned n = *cntg; if (n > CAP) n = CAP;
  int lane = threadIdx.x & 63;
  unsigned wv = blockIdx.x*4 + (threadIdx.x >> 6);
  for (unsigned e = wv; e < n; e += 256) {
    unsigned ent = list[e];
    int row = (int)(ent >> 7), col = (int)(ent & 127);
    int bk = row >> 7;
    const float* a = ctxall + row_off(row);
    const float* b = ctxall + bk*2*LD2 + LD2 + col*ND;
    float d = 0.f;
    #pragma unroll
    for (int i = 0; i < 3; i++) {
      f32x4 va = *(const f32x4*)(a + lane*12 + i*4);
      f32x4 vb = *(const f32x4*)(b + lane*12 + i*4);
      d += va[0]*vb[0] + va[1]*vb[1] + va[2]*vb[2] + va[3]*vb[3];
    }
    #pragma unroll
    for (int m = 1; m < 64; m <<= 1) d += __shfl_xor(d, m);
    if (lane == 0) {
      float cn = norm[row], en = norm[NROW + bk*NL + col];
      float s = d / (cn*en + EPSF);
      unsigned su = __float_as_uint(s);
      unsigned ord = (su & 0x80000000u) ? ~su : (su | 0x80000000u);
      unsigned long long key = ((unsigned long long)ord << 32) | (unsigned)(127 - col);
      atomicMax(&amax2[row], key);
    }
  }
}

// ---------------- K3 v2: output-partitioned MLP (acc-in-AGPR) --------------
// Block = 128 rows x ALL 768 outputs, 512 thr = 8 waves. Wave w owns the 6
// output tiles nt = w + 8*i. Accumulators acc[6][8] (192 regs) live in AGPRs
// for the whole kernel (k3_b proved 128V + 192A fits at 2 waves/SIMD).
// Per 32-wide K-step: A[128][32] staged ONCE in an 8 KB LDS tile (from the
// bf16 mirror, L3-hot) and shared by all waves (8 ds_read_b128/wave); the 6
// B-frags come straight from L2-hot w1t (no LDS round trip). This cuts k3's
// LDS traffic 12x (2.4 GB -> 0.2 GB) -> MFMA-bound. ks handled in pairs so
// B-reads consume full 128-B lines of the XOR-grouped w1t layout.
// Epilogue: relu/w2 partials -> shfl over eloc -> 4 KB LDS cross-wave reduce.
__global__ __launch_bounds__(512, 2) void k3_mlp_c(
    const __bf16* __restrict__ abf16, const float* __restrict__ norm,
    const __bf16* __restrict__ w1t, const float* __restrict__ b1,
    const float* __restrict__ w2, float* __restrict__ val) {
  __shared__ alignas(16) __bf16 atile[2][128*32];   // 2 x 8 KB A tiles
  __shared__ float red[8][128];                      // cross-wave partials
  int tid = threadIdx.x;
  int wave = tid >> 6, lane = tid & 63;
  int quad = lane >> 4, eloc = lane & 15;
  int rbase = blockIdx.x * 128;
  int arow = tid >> 2, acol = (tid & 3) * 8;         // 512 thr x 16B = one 8KB tile

  // stage ks=0 immediately; overlaps the b1/w2 preload below
  {
    const __bf16* s0 = abf16 + (size_t)(rbase + arow)*ND + acol;
    __builtin_amdgcn_global_load_lds(
      (const __attribute__((address_space(1))) unsigned int*)s0,
      (__attribute__((address_space(3))) unsigned int*)(&atile[0][0] + tid*8),
      16, 0, 0);
  }

  float b1v[6], w2v[6];
  #pragma unroll
  for (int i = 0; i < 6; i++) {
    int out = (wave + 8*i)*16 + eloc;
    b1v[i] = b1[out];
    w2v[i] = w2[out];
  }

  f32x4 acc[6][8];
  #pragma unroll
  for (int i = 0; i < 6; i++)
    #pragma unroll
    for (int rt = 0; rt < 8; rt++) acc[i][rt] = (f32x4){0,0,0,0};

  int p = 0;
  for (int ksp = 0; ksp < 12; ksp++) {
    int ks0 = ksp*2;
    // ---- first half: compute ks0 from atile[p], stage ks0+1
    __syncthreads();                       // atile[p] staged & prior reads done
    {
      const __bf16* s1 = abf16 + (size_t)(rbase + arow)*ND + (ks0+1)*32 + acol;
      __builtin_amdgcn_global_load_lds(
        (const __attribute__((address_space(1))) unsigned int*)s1,
        (__attribute__((address_space(3))) unsigned int*)(&atile[p^1][0] + tid*8),
        16, 0, 0);
    }
    bf16x8 bf0[6], bf1[6];                 // both ks of the pair: full 128B lines
    #pragma unroll
    for (int i = 0; i < 6; i++) {
      const __bf16* brow = w1t + ((wave + 8*i)*16 + eloc)*ND;
      int g0 = ks0*4 + quad;
      bf0[i] = *(const bf16x8*)(brow + ((g0       ^ (eloc & 7))*8));
      bf1[i] = *(const bf16x8*)(brow + (((g0 + 4) ^ (eloc & 7))*8));
    }
    #pragma unroll
    for (int rt = 0; rt < 8; rt++) {
      bf16x8 af = *(const bf16x8*)&atile[p][(rt*16 + eloc)*32 + quad*8];
      #pragma unroll
      for (int i = 0; i < 6; i++)
        acc[i][rt] = __builtin_amdgcn_mfma_f32_16x16x32_bf16(af, bf0[i], acc[i][rt], 0, 0, 0);
    }
    p ^= 1;
    // ---- second half: compute ks0+1 from atile[p], stage ks0+2
    __syncthreads();
    if (ksp < 11) {
      const __bf16* s2 = abf16 + (size_t)(rbase + arow)*ND + (ks0+2)*32 + acol;
      __builtin_amdgcn_global_load_lds(
        (const __attribute__((address_space(1))) unsigned int*)s2,
        (__attribute__((address_space(3))) unsigned int*)(&atile[p^1][0] + tid*8),
        16, 0, 0);
    }
    #pragma unroll
    for (int rt = 0; rt < 8; rt++) {
      bf16x8 af = *(const bf16x8*)&atile[p][(rt*16 + eloc)*32 + quad*8];
      #pragma unroll
      for (int i = 0; i < 6; i++)
        acc[i][rt] = __builtin_amdgcn_mfma_f32_16x16x32_bf16(af, bf1[i], acc[i][rt], 0, 0, 0);
    }
    p ^= 1;
  }

  // epilogue: h = acc*rinv (row norm), relu, dot w2; sum over this wave's 96
  // outputs via shfl over the eloc bits; cross-wave sum via LDS.
  #pragma unroll
  for (int rt = 0; rt < 8; rt++) {
    f32x4 nv = *(const f32x4*)&norm[rbase + rt*16 + quad*4];
    f32x4 rv;
    #pragma unroll
    for (int r = 0; r < 4; r++) rv[r] = 1.0f / nv[r];
    f32x4 s = {0,0,0,0};
    #pragma unroll
    for (int i = 0; i < 6; i++)
      #pragma unroll
      for (int r = 0; r < 4; r++)
        s[r] += fmaxf(acc[i][rt][r]*rv[r] + b1v[i], 0.f) * w2v[i];
    #pragma unroll
    for (int m = 1; m < 16; m <<= 1)
      #pragma unroll
      for (int r = 0; r < 4; r++) s[r] += __shfl_xor(s[r], m);
    if (eloc == 0) *(f32x4*)&red[wave][rt*16 + quad*4] = s;
  }
  __syncthreads();
  if (tid < 128) {
    float tsum = 0.f;
    #pragma unroll
    for (int wv = 0; wv < 8; wv++) tsum += red[wv][tid];
    val[rbase + tid] = tsum;
  }
}

// ---------------- K3 (fallback): original f32-sourced MLP ------------------
__global__ __launch_bounds__(256, 2) void k3_mlp(
    const float* __restrict__ ctxall, const float* __restrict__ norm,
    const __bf16* __restrict__ w1t, const float* __restrict__ b1,
    const float* __restrict__ w2, float* __restrict__ val) {
  __shared__ alignas(16) __bf16 btile[2][16*768];   // 2 x 24 KB w1t tiles
  int tid = threadIdx.x;
  int wave = tid >> 6, lane = tid & 63;
  int quad = lane >> 4, eloc = lane & 15;
  int rbase = blockIdx.x*128 + wave*32;

  #pragma unroll
  for (int i = 0; i < 6; i++) {
    __builtin_amdgcn_global_load_lds(
      (const __attribute__((address_space(1))) unsigned int*)(w1t + (i*256 + tid)*8),
      (__attribute__((address_space(3))) unsigned int*)(&btile[0][0] + (i*256 + tid)*8),
      16, 0, 0);
  }

  bf16x8 afrag[2][24];
  #pragma unroll
  for (int s = 0; s < 2; s++) {
    int r = rbase + s*16 + eloc;
    const float* src = ctxall + row_off(r);
    float rinv = 1.0f / norm[r];
    #pragma unroll
    for (int ks = 0; ks < 24; ks++) {
      const float* sp = src + ks*32 + quad*8;
      f32x4 v0 = *(const f32x4*)sp;
      f32x4 v1 = *(const f32x4*)(sp + 4);
      bf16x8 a;
      a[0] = (__bf16)(v0[0]*rinv); a[1] = (__bf16)(v0[1]*rinv);
      a[2] = (__bf16)(v0[2]*rinv); a[3] = (__bf16)(v0[3]*rinv);
      a[4] = (__bf16)(v1[0]*rinv); a[5] = (__bf16)(v1[1]*rinv);
      a[6] = (__bf16)(v1[2]*rinv); a[7] = (__bf16)(v1[3]*rinv);
      afrag[s][ks] = a;
    }
  }

  float oacc[2][4] = {{0,0,0,0},{0,0,0,0}};
  int p = 0;
  for (int nt = 0; nt < 48; nt++) {
    __syncthreads();
    if (nt < 47) {
      const __bf16* gsrc = w1t + (nt+1)*16*ND;
      #pragma unroll
      for (int i = 0; i < 6; i++) {
        __builtin_amdgcn_global_load_lds(
          (const __attribute__((address_space(1))) unsigned int*)(gsrc + (i*256 + tid)*8),
          (__attribute__((address_space(3))) unsigned int*)(&btile[p^1][0] + (i*256 + tid)*8),
          16, 0, 0);
      }
    }
    f32x4 h0 = {0,0,0,0}, h1 = {0,0,0,0};
    #pragma unroll
    for (int ks = 0; ks < 24; ks++) {
      int g = ks*4 + quad;
      bf16x8 bfrag = *(const bf16x8*)(&btile[p][0] + eloc*ND + ((g ^ (eloc & 7))*8));
      h0 = __builtin_amdgcn_mfma_f32_16x16x32_bf16(afrag[0][ks], bfrag, h0, 0, 0, 0);
      h1 = __builtin_amdgcn_mfma_f32_16x16x32_bf16(afrag[1][ks], bfrag, h1, 0, 0, 0);
    }
    float b1v = b1[nt*16 + eloc];
    float w2v = w2[nt*16 + eloc];
    #pragma unroll
    for (int rr = 0; rr < 4; rr++) {
      oacc[0][rr] += fmaxf(h0[rr] + b1v, 0.f) * w2v;
      oacc[1][rr] += fmaxf(h1[rr] + b1v, 0.f) * w2v;
    }
    p ^= 1;
  }
  #pragma unroll
  for (int m = 1; m < 16; m <<= 1)
    #pragma unroll
    for (int s = 0; s < 2; s++)
      #pragma unroll
      for (int rr = 0; rr < 4; rr++)
        oacc[s][rr] += __shfl_xor(oacc[s][rr], m);
  if (eloc == 0) {
    #pragma unroll
    for (int s = 0; s < 2; s++)
      #pragma unroll
      for (int rr = 0; rr < 4; rr++)
        val[rbase + s*16 + quad*4 + rr] = oacc[s][rr];
  }
}

// ---------------- K4: gather-add final output (with fixup override) --------
__global__ void k4_out(const float* __restrict__ val, const int* __restrict__ amax,
                       const unsigned long long* __restrict__ amax2,
                       const float* __restrict__ b2, float* __restrict__ out) {
  int i = blockIdx.x*256 + threadIdx.x;      // < NROW
  int bk = i >> 7;
  unsigned long long k = amax2[i];
  int a = k ? (127 - (int)(k & 127ull)) : amax[i];
  out[i] = val[i] + val[NROW + bk*NL + a] + 2.0f*b2[0];
}

extern "C" void kernel_launch(void* const* d_in, const int* in_sizes, int n_in,
                              void* d_out, int out_size, void* d_ws, size_t ws_size,
                              hipStream_t stream) {
  const float* ctxall = (const float*)d_in[0];
  const float* w1 = (const float*)d_in[1];
  const float* b1 = (const float*)d_in[2];
  const float* w2 = (const float*)d_in[3];
  const float* b2 = (const float*)d_in[4];
  float* out = (float*)d_out;

  char* ws = (char*)d_ws;
  float*    norm = (float*)ws;                        // [0, 262144)
  int*      amax = (int*)(ws + 262144);               // [262144, 393216)
  float*    val  = (float*)(ws + 393216);             // [393216, 655360)
  __bf16*   w1t  = (__bf16*)(ws + 655360);            // [655360, 1835008)
  unsigned long long* amax2 = (unsigned long long*)(ws + 1835008);  // 256 KB
  unsigned* cntg = (unsigned*)(ws + 2097152);         // 4 B
  unsigned* list = (unsigned*)(ws + 2097156);         // 64 KB

  // bf16 A-mirror for k3 (96 MiB) at +8 MiB, if the workspace is big enough.
  const size_t abf_off = 8ull << 20;
  const size_t abf_bytes = (size_t)2*NROW*ND*sizeof(__bf16);   // 100663296
  __bf16* abf16 = (ws_size >= abf_off + abf_bytes) ? (__bf16*)(ws + abf_off)
                                                   : (__bf16*)0;

  hipLaunchKernelGGL(k0_w1t,     dim3(144),        dim3(256), 0, stream, w1, w1t, amax2, cntg);
  hipLaunchKernelGGL(k2a_screen, dim3(NBK),        dim3(512), 0, stream, ctxall, norm, amax, cntg, list, abf16);
  hipLaunchKernelGGL(k2b_rescore,dim3(64),         dim3(256), 0, stream, ctxall, norm, cntg, list, amax2);
  if (abf16) {
    hipLaunchKernelGGL(k3_mlp_c, dim3(2*NROW/128), dim3(512), 0, stream, abf16, norm, w1t, b1, w2, val);
  } else {
    hipLaunchKernelGGL(k3_mlp,   dim3(2*NROW/128), dim3(256), 0, stream, ctxall, norm, w1t, b1, w2, val);
  }
  hipLaunchKernelGGL(k4_out,     dim3(NROW/256),   dim3(256), 0, stream, val, amax, amax2, b2, out);
}

// Round 5
// 450.121 us; speedup vs baseline: 1.0219x; 1.0219x over previous
//
#include <hip/hip_runtime.h>
#include <hip/hip_bf16.h>
#include <stdint.h>

#define NB 4
#define NK 64
#define NL 128
#define ND 768
#define NBK (NB*NK)        // 256
#define NROW (NBK*NL)      // 32768
#define LD2 (NL*ND)        // 98304
#define EPSF 1e-8f
#define THETA 2e-3f        // candidate window on dot*einv scale (~75 sigma of split-bf16 error)
#define CAP 16384          // candidate list capacity (expect ~300)
#define TSTR 40            // k2a LDS row stride (80B = 5 slots, odd mod 8)

typedef __bf16 bf16x8 __attribute__((ext_vector_type(8)));
typedef float  f32x4  __attribute__((ext_vector_type(4)));

// Row space r in [0, 2*NROW): [0,NROW) = ctx rows (bk=r>>7, l=r&127),
// [NROW,2*NROW) = ent rows. Returns float offset into context tensor.
__device__ __forceinline__ int row_off(int r) {
  if (r < NROW) return r*ND + (r >> 7)*LD2;
  int r2 = r - NROW;
  return r2*ND + (r2 >> 7)*LD2 + LD2;
}

// ---------------- K0: w1 -> w1t (row layout) + w1f (fragment-major) --------
// w1f packs the exact MFMA B-fragment each (out-tile nt, kstep ks) needs:
// w1f[((nt*24+ks)*64 + lane)*8 + j] = w1[ks*32+quad*8+j][nt*16+eloc]
// (lane = quad*16+eloc). k3's B-load then reads 1KB fully-coalesced per
// instruction — fixes round-4's 16-line-divergent B loads (TA-bound, 22%
// MfmaUtil). Also zero-inits fixup state.
__global__ __launch_bounds__(256) void k0_w1t(const float* __restrict__ w1,
                                              __bf16* __restrict__ w1t,
                                              __bf16* __restrict__ w1f,
                                              unsigned long long* __restrict__ amax2,
                                              unsigned* __restrict__ cntg) {
  __shared__ float tile[64][68];               // [k][e], +4 pad
  int idx = blockIdx.x*256 + threadIdx.x;
  if (idx < NROW) amax2[idx] = 0ull;           // fixup keys zeroed every launch
  if (idx == 0) *cntg = 0u;
  int kb = (blockIdx.x / 12) * 64, eb = (blockIdx.x % 12) * 64;
  int t = threadIdx.x;
  int r = t >> 2, c0 = (t & 3) * 16;
  #pragma unroll
  for (int j = 0; j < 4; j++) {
    f32x4 v = *(const f32x4*)(w1 + (kb + r)*ND + eb + c0 + j*4);
    *(f32x4*)&tile[r][c0 + j*4] = v;
  }
  __syncthreads();
  int e = t & 63, gi = t >> 6;
  int eg = eb + e;
  #pragma unroll
  for (int g2 = 0; g2 < 2; g2++) {
    int g = gi*2 + g2;
    bf16x8 o;
    #pragma unroll
    for (int j = 0; j < 8; j++) o[j] = (__bf16)tile[g*8 + j][e];
    int G = (kb >> 3) + (g ^ (eg & 7));        // XOR layout (k3_b fallback)
    *(bf16x8*)(w1t + eg*ND + G*8) = o;
  }
  // fragment-major pack: this block covers 4 nt-tiles x 2 ks-steps = 8 frags
  // of 64 lanes; 512 lane-tasks over 256 threads.
  #pragma unroll
  for (int rr = 0; rr < 2; rr++) {
    int task = t + rr*256;
    int fi = task >> 6, l = task & 63;
    int nt_loc = fi & 3, ks_loc = fi >> 2;
    int quad = l >> 4, eloc = l & 15;
    bf16x8 o;
    #pragma unroll
    for (int j = 0; j < 8; j++)
      o[j] = (__bf16)tile[ks_loc*32 + quad*8 + j][nt_loc*16 + eloc];
    int nt = (eb >> 4) + nt_loc, ks = (kb >> 5) + ks_loc;
    *(bf16x8*)(w1f + (size_t)((nt*24 + ks)*64 + l)*8) = o;
  }
}

// split f32x4 into truncated-bf16 hi (packed pair uints) and exact-remainder
// lo (truncated to bf16); accumulate sum of squares of the f32 values.
__device__ __forceinline__ void cvt4(f32x4 v, unsigned& hp0, unsigned& hp1,
                                     unsigned& lp0, unsigned& lp1, float& sq) {
  unsigned u0 = __float_as_uint(v[0]), u1 = __float_as_uint(v[1]);
  unsigned u2 = __float_as_uint(v[2]), u3 = __float_as_uint(v[3]);
  hp0 = (u1 & 0xffff0000u) | (u0 >> 16);
  hp1 = (u3 & 0xffff0000u) | (u2 >> 16);
  float l0 = v[0] - __uint_as_float(u0 & 0xffff0000u);   // exact (Sterbenz)
  float l1 = v[1] - __uint_as_float(u1 & 0xffff0000u);
  float l2 = v[2] - __uint_as_float(u2 & 0xffff0000u);
  float l3 = v[3] - __uint_as_float(u3 & 0xffff0000u);
  lp0 = (__float_as_uint(l1) & 0xffff0000u) | (__float_as_uint(l0) >> 16);
  lp1 = (__float_as_uint(l3) & 0xffff0000u) | (__float_as_uint(l2) >> 16);
  sq += v[0]*v[0] + v[1]*v[1] + v[2]*v[2] + v[3]*v[3];
}

// RNE-rounded bf16x8 from two f32x4 (for the k3 A-mirror).
__device__ __forceinline__ bf16x8 rnd8(f32x4 a, f32x4 b) {
  bf16x8 o;
  o[0] = (__bf16)a[0]; o[1] = (__bf16)a[1]; o[2] = (__bf16)a[2]; o[3] = (__bf16)a[3];
  o[4] = (__bf16)b[0]; o[5] = (__bf16)b[1]; o[6] = (__bf16)b[2]; o[7] = (__bf16)b[3];
  return o;
}

// ---------------- K2a: MFMA cosine screen + argmax + norms + candidates ----
// One block per bk: 128 ctx x 128 ent x K=768. 512 thr = 8 waves, wave w owns
// rows w*16..+15, all 128 cols (8 col-tiles), acc = 3-product split-bf16 sum.
// Also writes a rounded-bf16 mirror of each row for k3.
__global__ __launch_bounds__(512) void k2a_screen(
    const float* __restrict__ ctxall, float* __restrict__ norm,
    int* __restrict__ amax, unsigned* __restrict__ cntg,
    unsigned* __restrict__ list, __bf16* __restrict__ abf16) {
  __shared__ alignas(16) __bf16 tiles[2][4][128*TSTR];  // [buf][ahi,alo,bhi,blo]
  __shared__ float einv_s[128];
  int bk = blockIdx.x;
  int t = threadIdx.x;
  int mat = t >> 8, row = (t >> 1) & 127, kh = (t & 1) * 16;
  const float* src = ctxall + bk*2*LD2 + mat*LD2 + row*ND + kh;
  int w = t >> 6, lane = t & 63, quad = lane >> 4, eloc = lane & 15;
  __bf16* arow = abf16 ? (abf16 + (size_t)((mat ? NROW : 0) + bk*NL + row)*ND + kh)
                       : (__bf16*)0;

  f32x4 pv[4];
  #pragma unroll
  for (int i = 0; i < 4; i++) pv[i] = *(const f32x4*)(src + i*4);
  float sq = 0.f;
  f32x4 acc[8];
  #pragma unroll
  for (int ct = 0; ct < 8; ct++) acc[ct] = (f32x4){0,0,0,0};

  int p = 0;
  for (int kt = 0; kt < 24; kt++) {
    // convert current prefetch regs -> LDS[p]
    unsigned h0,h1,h2,h3, l0,l1,l2,l3;
    cvt4(pv[0], h0, h1, l0, l1, sq);
    cvt4(pv[1], h2, h3, l2, l3, sq);
    __bf16* hdst = &tiles[p][2*mat  ][row*TSTR + kh];
    __bf16* ldst = &tiles[p][2*mat+1][row*TSTR + kh];
    *(uint4*)hdst = make_uint4(h0,h1,h2,h3);
    *(uint4*)ldst = make_uint4(l0,l1,l2,l3);
    bf16x8 rb0, rb1;
    if (arow) rb0 = rnd8(pv[0], pv[1]);
    cvt4(pv[2], h0, h1, l0, l1, sq);
    cvt4(pv[3], h2, h3, l2, l3, sq);
    *((uint4*)hdst + 1) = make_uint4(h0,h1,h2,h3);
    *((uint4*)ldst + 1) = make_uint4(l0,l1,l2,l3);
    if (arow) rb1 = rnd8(pv[2], pv[3]);
    __syncthreads();
    if (arow) {                                // A-mirror store (fire & forget)
      *(bf16x8*)(arow + kt*32) = rb0;
      *(bf16x8*)(arow + kt*32 + 8) = rb1;
    }
    if (kt < 23) {                             // prefetch next Kt (flies over compute)
      const float* s2 = src + (kt+1)*32;
      #pragma unroll
      for (int i = 0; i < 4; i++) pv[i] = *(const f32x4*)(s2 + i*4);
    }
    // compute: A-frag rows w*16+eloc, k=quad*8+j
    bf16x8 ah = *(const bf16x8*)&tiles[p][0][(w*16+eloc)*TSTR + quad*8];
    bf16x8 al = *(const bf16x8*)&tiles[p][1][(w*16+eloc)*TSTR + quad*8];
    #pragma unroll
    for (int ct = 0; ct < 8; ct++) {
      bf16x8 bh = *(const bf16x8*)&tiles[p][2][(ct*16+eloc)*TSTR + quad*8];
      bf16x8 bl = *(const bf16x8*)&tiles[p][3][(ct*16+eloc)*TSTR + quad*8];
      acc[ct] = __builtin_amdgcn_mfma_f32_16x16x32_bf16(al, bh, acc[ct], 0, 0, 0);
      acc[ct] = __builtin_amdgcn_mfma_f32_16x16x32_bf16(ah, bl, acc[ct], 0, 0, 0);
      acc[ct] = __builtin_amdgcn_mfma_f32_16x16x32_bf16(ah, bh, acc[ct], 0, 0, 0);
    }
    p ^= 1;
  }

  // norms: thread pair (t, t^1) holds the two k-halves of one row
  float stot = sq + __shfl_xor(sq, 1);
  if ((t & 1) == 0) {
    float n = sqrtf(stot);
    if (mat == 0) norm[bk*NL + row] = n;
    else { norm[NROW + bk*NL + row] = n; einv_s[row] = 1.0f / n; }
  }
  __syncthreads();

  // epilogue: per-row argmax of acc*einv + theta-window candidate push
  #pragma unroll
  for (int rr = 0; rr < 4; rr++) {
    float sc[8];
    float best = -3.0e38f; int bcol = 0;
    #pragma unroll
    for (int ct = 0; ct < 8; ct++) {
      sc[ct] = acc[ct][rr] * einv_s[ct*16 + eloc];
      int col = ct*16 + eloc;
      if (sc[ct] > best) { best = sc[ct]; bcol = col; }
    }
    #pragma unroll
    for (int m = 1; m < 16; m <<= 1) {
      float ov = __shfl_xor(best, m);
      int   oc = __shfl_xor(bcol, m);
      if (ov > best || (ov == best && oc < bcol)) { best = ov; bcol = oc; }
    }
    int grow = bk*NL + w*16 + quad*4 + rr;
    if (eloc == 0) amax[grow] = bcol;
    int cnt = 0;
    #pragma unroll
    for (int ct = 0; ct < 8; ct++) cnt += (sc[ct] >= best - THETA) ? 1 : 0;
    #pragma unroll
    for (int m = 1; m < 16; m <<= 1) cnt += __shfl_xor(cnt, m);
    if (cnt >= 2) {                            // near-tie: exact rescore needed
      #pragma unroll
      for (int ct = 0; ct < 8; ct++) {
        if (sc[ct] >= best - THETA) {
          unsigned idx = atomicAdd(cntg, 1u);
          if (idx < CAP) list[idx] = ((unsigned)grow << 7) | (unsigned)(ct*16 + eloc);
        }
      }
    }
  }
}

// ---------------- K2b: exact f32 rescore of near-tie candidates ------------
__global__ __launch_bounds__(256) void k2b_rescore(
    const float* __restrict__ ctxall, const float* __restrict__ norm,
    const unsigned* __restrict__ cntg, const unsigned* __restrict__ list,
    unsigned long long* __restrict__ amax2) {
  unsigned n = *cntg; if (n > CAP) n = CAP;
  int lane = threadIdx.x & 63;
  unsigned wv = blockIdx.x*4 + (threadIdx.x >> 6);
  for (unsigned e = wv; e < n; e += 256) {
    unsigned ent = list[e];
    int row = (int)(ent >> 7), col = (int)(ent & 127);
    int bk = row >> 7;
    const float* a = ctxall + row_off(row);
    const float* b = ctxall + bk*2*LD2 + LD2 + col*ND;
    float d = 0.f;
    #pragma unroll
    for (int i = 0; i < 3; i++) {
      f32x4 va = *(const f32x4*)(a + lane*12 + i*4);
      f32x4 vb = *(const f32x4*)(b + lane*12 + i*4);
      d += va[0]*vb[0] + va[1]*vb[1] + va[2]*vb[2] + va[3]*vb[3];
    }
    #pragma unroll
    for (int m = 1; m < 64; m <<= 1) d += __shfl_xor(d, m);
    if (lane == 0) {
      float cn = norm[row], en = norm[NROW + bk*NL + col];
      float s = d / (cn*en + EPSF);
      unsigned su = __float_as_uint(s);
      unsigned ord = (su & 0x80000000u) ? ~su : (su | 0x80000000u);
      unsigned long long key = ((unsigned long long)ord << 32) | (unsigned)(127 - col);
      atomicMax(&amax2[row], key);
    }
  }
}

// ---------------- K3 v2b: output-partitioned MLP, coalesced B --------------
// Block = 128 rows x ALL 768 outputs, 512 thr = 8 waves. Wave w owns the 6
// output tiles nt = w + 8*i; acc[6][8] (192 regs) in AGPRs. Per 32-wide
// K-step: A[128][32] staged ONCE in an 8 KB LDS tile (bf16 mirror, L3-hot),
// shared by all waves; B-frags from the fragment-major w1f (L2-hot) — each
// load is 1 KB fully coalesced (round-4's 16-line-divergent w1t-row reads
// were TA-bound at 22% MfmaUtil / 143 us).
__global__ __launch_bounds__(512, 2) void k3_mlp_c(
    const __bf16* __restrict__ abf16, const float* __restrict__ norm,
    const __bf16* __restrict__ w1f, const float* __restrict__ b1,
    const float* __restrict__ w2, float* __restrict__ val) {
  __shared__ alignas(16) __bf16 atile[2][128*32];   // 2 x 8 KB A tiles
  __shared__ float red[8][128];                      // cross-wave partials
  int tid = threadIdx.x;
  int wave = tid >> 6, lane = tid & 63;
  int quad = lane >> 4, eloc = lane & 15;
  int rbase = blockIdx.x * 128;
  int arow = tid >> 2, acol = (tid & 3) * 8;         // 512 thr x 16B = one 8KB tile

  // stage ks=0 immediately; overlaps the b1/w2 preload below
  {
    const __bf16* s0 = abf16 + (size_t)(rbase + arow)*ND + acol;
    __builtin_amdgcn_global_load_lds(
      (const __attribute__((address_space(1))) unsigned int*)s0,
      (__attribute__((address_space(3))) unsigned int*)(&atile[0][0] + tid*8),
      16, 0, 0);
  }

  float b1v[6], w2v[6];
  #pragma unroll
  for (int i = 0; i < 6; i++) {
    int out = (wave + 8*i)*16 + eloc;
    b1v[i] = b1[out];
    w2v[i] = w2[out];
  }

  f32x4 acc[6][8];
  #pragma unroll
  for (int i = 0; i < 6; i++)
    #pragma unroll
    for (int rt = 0; rt < 8; rt++) acc[i][rt] = (f32x4){0,0,0,0};

  int p = 0;
  for (int ksp = 0; ksp < 12; ksp++) {
    int ks0 = ksp*2;
    // ---- first half: compute ks0 from atile[p], stage ks0+1
    __syncthreads();                       // atile[p] staged & prior reads done
    {
      const __bf16* s1 = abf16 + (size_t)(rbase + arow)*ND + (ks0+1)*32 + acol;
      __builtin_amdgcn_global_load_lds(
        (const __attribute__((address_space(1))) unsigned int*)s1,
        (__attribute__((address_space(3))) unsigned int*)(&atile[p^1][0] + tid*8),
        16, 0, 0);
    }
    bf16x8 bf0[6], bf1[6];                 // both ks of the pair, coalesced 1KB each
    #pragma unroll
    for (int i = 0; i < 6; i++) {
      const __bf16* fb = w1f + (size_t)(((wave + 8*i)*24 + ks0)*64 + lane)*8;
      bf0[i] = *(const bf16x8*)fb;
      bf1[i] = *(const bf16x8*)(fb + 64*8);  // ks0+1 frag
    }
    #pragma unroll
    for (int rt = 0; rt < 8; rt++) {
      bf16x8 af = *(const bf16x8*)&atile[p][(rt*16 + eloc)*32 + quad*8];
      #pragma unroll
      for (int i = 0; i < 6; i++)
        acc[i][rt] = __builtin_amdgcn_mfma_f32_16x16x32_bf16(af, bf0[i], acc[i][rt], 0, 0, 0);
    }
    p ^= 1;
    // ---- second half: compute ks0+1 from atile[p], stage ks0+2
    __syncthreads();
    if (ksp < 11) {
      const __bf16* s2 = abf16 + (size_t)(rbase + arow)*ND + (ks0+2)*32 + acol;
      __builtin_amdgcn_global_load_lds(
        (const __attribute__((address_space(1))) unsigned int*)s2,
        (__attribute__((address_space(3))) unsigned int*)(&atile[p^1][0] + tid*8),
        16, 0, 0);
    }
    #pragma unroll
    for (int rt = 0; rt < 8; rt++) {
      bf16x8 af = *(const bf16x8*)&atile[p][(rt*16 + eloc)*32 + quad*8];
      #pragma unroll
      for (int i = 0; i < 6; i++)
        acc[i][rt] = __builtin_amdgcn_mfma_f32_16x16x32_bf16(af, bf1[i], acc[i][rt], 0, 0, 0);
    }
    p ^= 1;
  }

  // epilogue: h = acc*rinv (row norm), relu, dot w2; sum over this wave's 96
  // outputs via shfl over the eloc bits; cross-wave sum via LDS.
  #pragma unroll
  for (int rt = 0; rt < 8; rt++) {
    f32x4 nv = *(const f32x4*)&norm[rbase + rt*16 + quad*4];
    f32x4 rv;
    #pragma unroll
    for (int r = 0; r < 4; r++) rv[r] = 1.0f / nv[r];
    f32x4 s = {0,0,0,0};
    #pragma unroll
    for (int i = 0; i < 6; i++)
      #pragma unroll
      for (int r = 0; r < 4; r++)
        s[r] += fmaxf(acc[i][rt][r]*rv[r] + b1v[i], 0.f) * w2v[i];
    #pragma unroll
    for (int m = 1; m < 16; m <<= 1)
      #pragma unroll
      for (int r = 0; r < 4; r++) s[r] += __shfl_xor(s[r], m);
    if (eloc == 0) *(f32x4*)&red[wave][rt*16 + quad*4] = s;
  }
  __syncthreads();
  if (tid < 128) {
    float tsum = 0.f;
    #pragma unroll
    for (int wv = 0; wv < 8; wv++) tsum += red[wv][tid];
    val[rbase + tid] = tsum;
  }
}

// ---------------- K3 (fallback): original f32-sourced MLP ------------------
__global__ __launch_bounds__(256, 2) void k3_mlp(
    const float* __restrict__ ctxall, const float* __restrict__ norm,
    const __bf16* __restrict__ w1t, const float* __restrict__ b1,
    const float* __restrict__ w2, float* __restrict__ val) {
  __shared__ alignas(16) __bf16 btile[2][16*768];   // 2 x 24 KB w1t tiles
  int tid = threadIdx.x;
  int wave = tid >> 6, lane = tid & 63;
  int quad = lane >> 4, eloc = lane & 15;
  int rbase = blockIdx.x*128 + wave*32;

  #pragma unroll
  for (int i = 0; i < 6; i++) {
    __builtin_amdgcn_global_load_lds(
      (const __attribute__((address_space(1))) unsigned int*)(w1t + (i*256 + tid)*8),
      (__attribute__((address_space(3))) unsigned int*)(&btile[0][0] + (i*256 + tid)*8),
      16, 0, 0);
  }

  bf16x8 afrag[2][24];
  #pragma unroll
  for (int s = 0; s < 2; s++) {
    int r = rbase + s*16 + eloc;
    const float* src = ctxall + row_off(r);
    float rinv = 1.0f / norm[r];
    #pragma unroll
    for (int ks = 0; ks < 24; ks++) {
      const float* sp = src + ks*32 + quad*8;
      f32x4 v0 = *(const f32x4*)sp;
      f32x4 v1 = *(const f32x4*)(sp + 4);
      bf16x8 a;
      a[0] = (__bf16)(v0[0]*rinv); a[1] = (__bf16)(v0[1]*rinv);
      a[2] = (__bf16)(v0[2]*rinv); a[3] = (__bf16)(v0[3]*rinv);
      a[4] = (__bf16)(v1[0]*rinv); a[5] = (__bf16)(v1[1]*rinv);
      a[6] = (__bf16)(v1[2]*rinv); a[7] = (__bf16)(v1[3]*rinv);
      afrag[s][ks] = a;
    }
  }

  float oacc[2][4] = {{0,0,0,0},{0,0,0,0}};
  int p = 0;
  for (int nt = 0; nt < 48; nt++) {
    __syncthreads();
    if (nt < 47) {
      const __bf16* gsrc = w1t + (nt+1)*16*ND;
      #pragma unroll
      for (int i = 0; i < 6; i++) {
        __builtin_amdgcn_global_load_lds(
          (const __attribute__((address_space(1))) unsigned int*)(gsrc + (i*256 + tid)*8),
          (__attribute__((address_space(3))) unsigned int*)(&btile[p^1][0] + (i*256 + tid)*8),
          16, 0, 0);
      }
    }
    f32x4 h0 = {0,0,0,0}, h1 = {0,0,0,0};
    #pragma unroll
    for (int ks = 0; ks < 24; ks++) {
      int g = ks*4 + quad;
      bf16x8 bfrag = *(const bf16x8*)(&btile[p][0] + eloc*ND + ((g ^ (eloc & 7))*8));
      h0 = __builtin_amdgcn_mfma_f32_16x16x32_bf16(afrag[0][ks], bfrag, h0, 0, 0, 0);
      h1 = __builtin_amdgcn_mfma_f32_16x16x32_bf16(afrag[1][ks], bfrag, h1, 0, 0, 0);
    }
    float b1v = b1[nt*16 + eloc];
    float w2v = w2[nt*16 + eloc];
    #pragma unroll
    for (int rr = 0; rr < 4; rr++) {
      oacc[0][rr] += fmaxf(h0[rr] + b1v, 0.f) * w2v;
      oacc[1][rr] += fmaxf(h1[rr] + b1v, 0.f) * w2v;
    }
    p ^= 1;
  }
  #pragma unroll
  for (int m = 1; m < 16; m <<= 1)
    #pragma unroll
    for (int s = 0; s < 2; s++)
      #pragma unroll
      for (int rr = 0; rr < 4; rr++)
        oacc[s][rr] += __shfl_xor(oacc[s][rr], m);
  if (eloc == 0) {
    #pragma unroll
    for (int s = 0; s < 2; s++)
      #pragma unroll
      for (int rr = 0; rr < 4; rr++)
        val[rbase + s*16 + quad*4 + rr] = oacc[s][rr];
  }
}

// ---------------- K4: gather-add final output (with fixup override) --------
__global__ void k4_out(const float* __restrict__ val, const int* __restrict__ amax,
                       const unsigned long long* __restrict__ amax2,
                       const float* __restrict__ b2, float* __restrict__ out) {
  int i = blockIdx.x*256 + threadIdx.x;      // < NROW
  int bk = i >> 7;
  unsigned long long k = amax2[i];
  int a = k ? (127 - (int)(k & 127ull)) : amax[i];
  out[i] = val[i] + val[NROW + bk*NL + a] + 2.0f*b2[0];
}

extern "C" void kernel_launch(void* const* d_in, const int* in_sizes, int n_in,
                              void* d_out, int out_size, void* d_ws, size_t ws_size,
                              hipStream_t stream) {
  const float* ctxall = (const float*)d_in[0];
  const float* w1 = (const float*)d_in[1];
  const float* b1 = (const float*)d_in[2];
  const float* w2 = (const float*)d_in[3];
  const float* b2 = (const float*)d_in[4];
  float* out = (float*)d_out;

  char* ws = (char*)d_ws;
  float*    norm = (float*)ws;                        // [0, 262144)
  int*      amax = (int*)(ws + 262144);               // [262144, 393216)
  float*    val  = (float*)(ws + 393216);             // [393216, 655360)
  __bf16*   w1t  = (__bf16*)(ws + 655360);            // [655360, 1835008)
  unsigned long long* amax2 = (unsigned long long*)(ws + 1835008);  // 256 KB
  unsigned* cntg = (unsigned*)(ws + 2097152);         // 4 B
  unsigned* list = (unsigned*)(ws + 2097156);         // 64 KB
  __bf16*   w1f  = (__bf16*)(ws + 2228224);           // 1.15 MB frag-major w1

  // bf16 A-mirror for k3 (96 MiB) at +8 MiB, if the workspace is big enough.
  const size_t abf_off = 8ull << 20;
  const size_t abf_bytes = (size_t)2*NROW*ND*sizeof(__bf16);   // 100663296
  __bf16* abf16 = (ws_size >= abf_off + abf_bytes) ? (__bf16*)(ws + abf_off)
                                                   : (__bf16*)0;

  hipLaunchKernelGGL(k0_w1t,     dim3(144),        dim3(256), 0, stream, w1, w1t, w1f, amax2, cntg);
  hipLaunchKernelGGL(k2a_screen, dim3(NBK),        dim3(512), 0, stream, ctxall, norm, amax, cntg, list, abf16);
  hipLaunchKernelGGL(k2b_rescore,dim3(64),         dim3(256), 0, stream, ctxall, norm, cntg, list, amax2);
  if (abf16) {
    hipLaunchKernelGGL(k3_mlp_c, dim3(2*NROW/128), dim3(512), 0, stream, abf16, norm, w1f, b1, w2, val);
  } else {
    hipLaunchKernelGGL(k3_mlp,   dim3(2*NROW/128), dim3(256), 0, stream, ctxall, norm, w1t, b1, w2, val);
  }
  hipLaunchKernelGGL(k4_out,     dim3(NROW/256),   dim3(256), 0, stream, val, amax, amax2, b2, out);
}

// Round 6
// 393.817 us; speedup vs baseline: 1.1680x; 1.1430x over previous
//
#include <hip/hip_runtime.h>
#include <hip/hip_bf16.h>
#include <stdint.h>

#define NB 4
#define NK 64
#define NL 128
#define ND 768
#define NBK (NB*NK)        // 256
#define NROW (NBK*NL)      // 32768
#define LD2 (NL*ND)        // 98304
#define EPSF 1e-8f
#define THETA 2e-3f        // candidate window on dot*einv scale (~75 sigma of split-bf16 error)
#define CAP 16384          // candidate list capacity (expect ~300)
#define BTS 56             // B-tile row stride: 112B = 7 slots, gcd(7,8)=1 -> 2-way (free), 16B-aligned

typedef __bf16 bf16x8 __attribute__((ext_vector_type(8)));
typedef float  f32x4  __attribute__((ext_vector_type(4)));

// Row space r in [0, 2*NROW): [0,NROW) = ctx rows (bk=r>>7, l=r&127),
// [NROW,2*NROW) = ent rows. Returns float offset into context tensor.
__device__ __forceinline__ int row_off(int r) {
  if (r < NROW) return r*ND + (r >> 7)*LD2;
  int r2 = r - NROW;
  return r2*ND + (r2 >> 7)*LD2 + LD2;
}

// ---------------- K0: w1 -> w1t transpose + zero-init of fixup state -------
__global__ __launch_bounds__(256) void k0_w1t(const float* __restrict__ w1,
                                              __bf16* __restrict__ w1t,
                                              unsigned long long* __restrict__ amax2,
                                              unsigned* __restrict__ cntg) {
  __shared__ float tile[64][68];               // [k][e], +4 pad
  int idx = blockIdx.x*256 + threadIdx.x;
  if (idx < NROW) amax2[idx] = 0ull;           // fixup keys zeroed every launch
  if (idx == 0) *cntg = 0u;
  int kb = (blockIdx.x / 12) * 64, eb = (blockIdx.x % 12) * 64;
  int t = threadIdx.x;
  int r = t >> 2, c0 = (t & 3) * 16;
  #pragma unroll
  for (int j = 0; j < 4; j++) {
    f32x4 v = *(const f32x4*)(w1 + (kb + r)*ND + eb + c0 + j*4);
    *(f32x4*)&tile[r][c0 + j*4] = v;
  }
  __syncthreads();
  int e = t & 63, gi = t >> 6;
  int eg = eb + e;
  #pragma unroll
  for (int g2 = 0; g2 < 2; g2++) {
    int g = gi*2 + g2;
    bf16x8 o;
    #pragma unroll
    for (int j = 0; j < 8; j++) o[j] = (__bf16)tile[g*8 + j][e];
    int G = (kb >> 3) + (g ^ (eg & 7));        // bank swizzle for k3's frag reads
    *(bf16x8*)(w1t + eg*ND + G*8) = o;
  }
}

// split f32x4 into truncated-bf16 hi (packed pair uints) and exact-remainder
// lo (truncated to bf16); accumulate sum of squares of the f32 values.
__device__ __forceinline__ void cvt4(f32x4 v, unsigned& hp0, unsigned& hp1,
                                     unsigned& lp0, unsigned& lp1, float& sq) {
  unsigned u0 = __float_as_uint(v[0]), u1 = __float_as_uint(v[1]);
  unsigned u2 = __float_as_uint(v[2]), u3 = __float_as_uint(v[3]);
  hp0 = (u1 & 0xffff0000u) | (u0 >> 16);
  hp1 = (u3 & 0xffff0000u) | (u2 >> 16);
  float l0 = v[0] - __uint_as_float(u0 & 0xffff0000u);   // exact (Sterbenz)
  float l1 = v[1] - __uint_as_float(u1 & 0xffff0000u);
  float l2 = v[2] - __uint_as_float(u2 & 0xffff0000u);
  float l3 = v[3] - __uint_as_float(u3 & 0xffff0000u);
  lp0 = (__float_as_uint(l1) & 0xffff0000u) | (__float_as_uint(l0) >> 16);
  lp1 = (__float_as_uint(l3) & 0xffff0000u) | (__float_as_uint(l2) >> 16);
  sq += v[0]*v[0] + v[1]*v[1] + v[2]*v[2] + v[3]*v[3];
}

// ---------------- K2a v2: cosine screen with 2-blocks/CU overlap -----------
// Round-0 structure ran 256 blocks = exactly 1 block/CU: every per-kt barrier
// idled the whole CU against HBM latency (~110 us vs 32 us floor). v2 splits
// each bk into TWO blocks of 64 ctx rows x 128 ent (grid 512, 256 thr = 4
// waves, LDS 72.5 KB -> 2 blocks/CU co-resident): one block computes while
// the other drains its stage. The bk-pair is mapped 256 apart in blockIdx ->
// same XCD (round-robin mod 8), co-resident, lockstep kt -> the duplicated
// ent-tile reads hit that XCD's L2 (HBM traffic stays ~201 MB).
// Staging: thread t<256 converts ent row t>>1 (khalf t&1); threads t<128 also
// convert ctx row t>>1. Compute/epilogue math identical to round 0, with
// grow offset + half*64. B-tile rows padded to BTS=56 (conflict-free reads).
__global__ __launch_bounds__(256) void k2a_screen(
    const float* __restrict__ ctxall, float* __restrict__ norm,
    int* __restrict__ amax, unsigned* __restrict__ cntg,
    unsigned* __restrict__ list) {
  __shared__ alignas(16) __bf16 Ah[2][64*32], Al[2][64*32];     // ctx hi/lo
  __shared__ alignas(16) __bf16 Bh[2][128*BTS], Bl[2][128*BTS]; // ent hi/lo
  __shared__ float einv_s[128];
  int bk = blockIdx.x & 255, half = blockIdx.x >> 8;
  int t = threadIdx.x;
  int w = t >> 6, lane = t & 63, quad = lane >> 4, eloc = lane & 15;
  bool hasA = (t < 128);                       // waves 0-1: A+B staging; 2-3: B only
  int srow = t >> 1, kh = (t & 1) * 16;
  const float* asrc = ctxall + bk*2*LD2 + (half*64 + srow)*ND + kh;
  const float* bsrc = ctxall + bk*2*LD2 + LD2 + srow*ND + kh;

  f32x4 pa[4], pb[4];
  #pragma unroll
  for (int i = 0; i < 4; i++) pb[i] = *(const f32x4*)(bsrc + i*4);
  if (hasA) {
    #pragma unroll
    for (int i = 0; i < 4; i++) pa[i] = *(const f32x4*)(asrc + i*4);
  }
  float sqa = 0.f, sqb = 0.f;
  f32x4 acc[8];
  #pragma unroll
  for (int ct = 0; ct < 8; ct++) acc[ct] = (f32x4){0,0,0,0};

  int p = 0;
  for (int kt = 0; kt < 24; kt++) {
    unsigned h0,h1,h2,h3, l0,l1,l2,l3;
    // ent staging (all threads)
    cvt4(pb[0], h0, h1, l0, l1, sqb);
    cvt4(pb[1], h2, h3, l2, l3, sqb);
    *(uint4*)&Bh[p][srow*BTS + kh] = make_uint4(h0,h1,h2,h3);
    *(uint4*)&Bl[p][srow*BTS + kh] = make_uint4(l0,l1,l2,l3);
    cvt4(pb[2], h0, h1, l0, l1, sqb);
    cvt4(pb[3], h2, h3, l2, l3, sqb);
    *((uint4*)&Bh[p][srow*BTS + kh] + 1) = make_uint4(h0,h1,h2,h3);
    *((uint4*)&Bl[p][srow*BTS + kh] + 1) = make_uint4(l0,l1,l2,l3);
    // ctx staging (waves 0-1)
    if (hasA) {
      cvt4(pa[0], h0, h1, l0, l1, sqa);
      cvt4(pa[1], h2, h3, l2, l3, sqa);
      *(uint4*)&Ah[p][srow*32 + kh] = make_uint4(h0,h1,h2,h3);
      *(uint4*)&Al[p][srow*32 + kh] = make_uint4(l0,l1,l2,l3);
      cvt4(pa[2], h0, h1, l0, l1, sqa);
      cvt4(pa[3], h2, h3, l2, l3, sqa);
      *((uint4*)&Ah[p][srow*32 + kh] + 1) = make_uint4(h0,h1,h2,h3);
      *((uint4*)&Al[p][srow*32 + kh] + 1) = make_uint4(l0,l1,l2,l3);
    }
    __syncthreads();
    if (kt < 23) {                             // prefetch next Kt over compute
      const float* b2 = bsrc + (kt+1)*32;
      #pragma unroll
      for (int i = 0; i < 4; i++) pb[i] = *(const f32x4*)(b2 + i*4);
      if (hasA) {
        const float* a2 = asrc + (kt+1)*32;
        #pragma unroll
        for (int i = 0; i < 4; i++) pa[i] = *(const f32x4*)(a2 + i*4);
      }
    }
    // compute: wave w owns ctx rows w*16..+15 (of this block's 64), all 128 ents
    bf16x8 ah = *(const bf16x8*)&Ah[p][(w*16+eloc)*32 + quad*8];
    bf16x8 al = *(const bf16x8*)&Al[p][(w*16+eloc)*32 + quad*8];
    #pragma unroll
    for (int ct = 0; ct < 8; ct++) {
      bf16x8 bh = *(const bf16x8*)&Bh[p][(ct*16+eloc)*BTS + quad*8];
      bf16x8 bl = *(const bf16x8*)&Bl[p][(ct*16+eloc)*BTS + quad*8];
      acc[ct] = __builtin_amdgcn_mfma_f32_16x16x32_bf16(al, bh, acc[ct], 0, 0, 0);
      acc[ct] = __builtin_amdgcn_mfma_f32_16x16x32_bf16(ah, bl, acc[ct], 0, 0, 0);
      acc[ct] = __builtin_amdgcn_mfma_f32_16x16x32_bf16(ah, bh, acc[ct], 0, 0, 0);
    }
    p ^= 1;
  }

  // norms: thread pair (t, t^1) holds the two k-halves of one staged row
  float stb = sqb + __shfl_xor(sqb, 1);
  if ((t & 1) == 0) {
    float n = sqrtf(stb);
    norm[NROW + bk*NL + srow] = n;             // both halves write same value (benign)
    einv_s[srow] = 1.0f / n;
  }
  if (hasA) {
    float sta = sqa + __shfl_xor(sqa, 1);
    if ((t & 1) == 0) norm[bk*NL + half*64 + srow] = sqrtf(sta);
  }
  __syncthreads();

  // epilogue: per-row argmax of acc*einv + theta-window candidate push
  #pragma unroll
  for (int rr = 0; rr < 4; rr++) {
    float sc[8];
    float best = -3.0e38f; int bcol = 0;
    #pragma unroll
    for (int ct = 0; ct < 8; ct++) {
      sc[ct] = acc[ct][rr] * einv_s[ct*16 + eloc];
      int col = ct*16 + eloc;
      if (sc[ct] > best) { best = sc[ct]; bcol = col; }
    }
    #pragma unroll
    for (int m = 1; m < 16; m <<= 1) {
      float ov = __shfl_xor(best, m);
      int   oc = __shfl_xor(bcol, m);
      if (ov > best || (ov == best && oc < bcol)) { best = ov; bcol = oc; }
    }
    int grow = bk*NL + half*64 + w*16 + quad*4 + rr;
    if (eloc == 0) amax[grow] = bcol;
    int cnt = 0;
    #pragma unroll
    for (int ct = 0; ct < 8; ct++) cnt += (sc[ct] >= best - THETA) ? 1 : 0;
    #pragma unroll
    for (int m = 1; m < 16; m <<= 1) cnt += __shfl_xor(cnt, m);
    if (cnt >= 2) {                            // near-tie: exact rescore needed
      #pragma unroll
      for (int ct = 0; ct < 8; ct++) {
        if (sc[ct] >= best - THETA) {
          unsigned idx = atomicAdd(cntg, 1u);
          if (idx < CAP) list[idx] = ((unsigned)grow << 7) | (unsigned)(ct*16 + eloc);
        }
      }
    }
  }
}

// ---------------- K2b: exact f32 rescore of near-tie candidates ------------
__global__ __launch_bounds__(256) void k2b_rescore(
    const float* __restrict__ ctxall, const float* __restrict__ norm,
    const unsigned* __restrict__ cntg, const unsigned* __restrict__ list,
    unsigned long long* __restrict__ amax2) {
  unsigned n = *cntg; if (n > CAP) n = CAP;
  int lane = threadIdx.x & 63;
  unsigned wv = blockIdx.x*4 + (threadIdx.x >> 6);
  for (unsigned e = wv; e < n; e += 256) {
    unsigned ent = list[e];
    int row = (int)(ent >> 7), col = (int)(ent & 127);
    int bk = row >> 7;
    const float* a = ctxall + row_off(row);
    const float* b = ctxall + bk*2*LD2 + LD2 + col*ND;
    float d = 0.f;
    #pragma unroll
    for (int i = 0; i < 3; i++) {
      f32x4 va = *(const f32x4*)(a + lane*12 + i*4);
      f32x4 vb = *(const f32x4*)(b + lane*12 + i*4);
      d += va[0]*vb[0] + va[1]*vb[1] + va[2]*vb[2] + va[3]*vb[3];
    }
    #pragma unroll
    for (int m = 1; m < 64; m <<= 1) d += __shfl_xor(d, m);
    if (lane == 0) {
      float cn = norm[row], en = norm[NROW + bk*NL + col];
      float s = d / (cn*en + EPSF);
      unsigned su = __float_as_uint(s);
      unsigned ord = (su & 0x80000000u) ? ~su : (su | 0x80000000u);
      unsigned long long key = ((unsigned long long)ord << 32) | (unsigned)(127 - col);
      atomicMax(&amax2[row], key);
    }
  }
}

// ---------------- K3: fused MLP per row (round-0 version, ~77 us) ----------
// Measured best of all k3 variants (f32-source+cvt beats both mirror forms:
// 77 vs 123 vs 144 us). 256 thr, 128 rows/block, (256,2): afrag in AGPRs.
__global__ __launch_bounds__(256, 2) void k3_mlp(
    const float* __restrict__ ctxall, const float* __restrict__ norm,
    const __bf16* __restrict__ w1t, const float* __restrict__ b1,
    const float* __restrict__ w2, float* __restrict__ val) {
  __shared__ alignas(16) __bf16 btile[2][16*768];   // 2 x 24 KB w1t tiles
  int tid = threadIdx.x;
  int wave = tid >> 6, lane = tid & 63;
  int quad = lane >> 4, eloc = lane & 15;
  int rbase = blockIdx.x*128 + wave*32;

  #pragma unroll
  for (int i = 0; i < 6; i++) {
    __builtin_amdgcn_global_load_lds(
      (const __attribute__((address_space(1))) unsigned int*)(w1t + (i*256 + tid)*8),
      (__attribute__((address_space(3))) unsigned int*)(&btile[0][0] + (i*256 + tid)*8),
      16, 0, 0);
  }

  bf16x8 afrag[2][24];
  #pragma unroll
  for (int s = 0; s < 2; s++) {
    int r = rbase + s*16 + eloc;
    const float* src = ctxall + row_off(r);
    float rinv = 1.0f / norm[r];
    #pragma unroll
    for (int ks = 0; ks < 24; ks++) {
      const float* sp = src + ks*32 + quad*8;
      f32x4 v0 = *(const f32x4*)sp;
      f32x4 v1 = *(const f32x4*)(sp + 4);
      bf16x8 a;
      a[0] = (__bf16)(v0[0]*rinv); a[1] = (__bf16)(v0[1]*rinv);
      a[2] = (__bf16)(v0[2]*rinv); a[3] = (__bf16)(v0[3]*rinv);
      a[4] = (__bf16)(v1[0]*rinv); a[5] = (__bf16)(v1[1]*rinv);
      a[6] = (__bf16)(v1[2]*rinv); a[7] = (__bf16)(v1[3]*rinv);
      afrag[s][ks] = a;
    }
  }

  float oacc[2][4] = {{0,0,0,0},{0,0,0,0}};
  int p = 0;
  for (int nt = 0; nt < 48; nt++) {
    __syncthreads();
    if (nt < 47) {
      const __bf16* gsrc = w1t + (nt+1)*16*ND;
      #pragma unroll
      for (int i = 0; i < 6; i++) {
        __builtin_amdgcn_global_load_lds(
          (const __attribute__((address_space(1))) unsigned int*)(gsrc + (i*256 + tid)*8),
          (__attribute__((address_space(3))) unsigned int*)(&btile[p^1][0] + (i*256 + tid)*8),
          16, 0, 0);
      }
    }
    f32x4 h0 = {0,0,0,0}, h1 = {0,0,0,0};
    #pragma unroll
    for (int ks = 0; ks < 24; ks++) {
      int g = ks*4 + quad;
      bf16x8 bfrag = *(const bf16x8*)(&btile[p][0] + eloc*ND + ((g ^ (eloc & 7))*8));
      h0 = __builtin_amdgcn_mfma_f32_16x16x32_bf16(afrag[0][ks], bfrag, h0, 0, 0, 0);
      h1 = __builtin_amdgcn_mfma_f32_16x16x32_bf16(afrag[1][ks], bfrag, h1, 0, 0, 0);
    }
    float b1v = b1[nt*16 + eloc];
    float w2v = w2[nt*16 + eloc];
    #pragma unroll
    for (int rr = 0; rr < 4; rr++) {
      oacc[0][rr] += fmaxf(h0[rr] + b1v, 0.f) * w2v;
      oacc[1][rr] += fmaxf(h1[rr] + b1v, 0.f) * w2v;
    }
    p ^= 1;
  }
  #pragma unroll
  for (int m = 1; m < 16; m <<= 1)
    #pragma unroll
    for (int s = 0; s < 2; s++)
      #pragma unroll
      for (int rr = 0; rr < 4; rr++)
        oacc[s][rr] += __shfl_xor(oacc[s][rr], m);
  if (eloc == 0) {
    #pragma unroll
    for (int s = 0; s < 2; s++)
      #pragma unroll
      for (int rr = 0; rr < 4; rr++)
        val[rbase + s*16 + quad*4 + rr] = oacc[s][rr];
  }
}

// ---------------- K4: gather-add final output (with fixup override) --------
__global__ void k4_out(const float* __restrict__ val, const int* __restrict__ amax,
                       const unsigned long long* __restrict__ amax2,
                       const float* __restrict__ b2, float* __restrict__ out) {
  int i = blockIdx.x*256 + threadIdx.x;      // < NROW
  int bk = i >> 7;
  unsigned long long k = amax2[i];
  int a = k ? (127 - (int)(k & 127ull)) : amax[i];
  out[i] = val[i] + val[NROW + bk*NL + a] + 2.0f*b2[0];
}

extern "C" void kernel_launch(void* const* d_in, const int* in_sizes, int n_in,
                              void* d_out, int out_size, void* d_ws, size_t ws_size,
                              hipStream_t stream) {
  const float* ctxall = (const float*)d_in[0];
  const float* w1 = (const float*)d_in[1];
  const float* b1 = (const float*)d_in[2];
  const float* w2 = (const float*)d_in[3];
  const float* b2 = (const float*)d_in[4];
  float* out = (float*)d_out;

  char* ws = (char*)d_ws;
  float*    norm = (float*)ws;                        // [0, 262144)
  int*      amax = (int*)(ws + 262144);               // [262144, 393216)
  float*    val  = (float*)(ws + 393216);             // [393216, 655360)
  __bf16*   w1t  = (__bf16*)(ws + 655360);            // [655360, 1835008)
  unsigned long long* amax2 = (unsigned long long*)(ws + 1835008);  // 256 KB
  unsigned* cntg = (unsigned*)(ws + 2097152);         // 4 B
  unsigned* list = (unsigned*)(ws + 2097156);         // 64 KB

  hipLaunchKernelGGL(k0_w1t,     dim3(144),        dim3(256), 0, stream, w1, w1t, amax2, cntg);
  hipLaunchKernelGGL(k2a_screen, dim3(2*NBK),      dim3(256), 0, stream, ctxall, norm, amax, cntg, list);
  hipLaunchKernelGGL(k2b_rescore,dim3(64),         dim3(256), 0, stream, ctxall, norm, cntg, list, amax2);
  hipLaunchKernelGGL(k3_mlp,     dim3(2*NROW/128), dim3(256), 0, stream, ctxall, norm, w1t, b1, w2, val);
  hipLaunchKernelGGL(k4_out,     dim3(NROW/256),   dim3(256), 0, stream, val, amax, amax2, b2, out);
}